// Round 21
// baseline (1119.411 us; speedup 1.0000x reference)
//
#include <hip/hip_runtime.h>
#include <math.h>

#define NPTS 4096
#define KNN 16
#define LN_EPS 1e-5f
#define DEPTH 20
#define CAP 24

// ---------------------------------------------------------------------------
// FROZEN ORACLE (r17/r20 PASS): np's neighbor sets = r17 serial algorithm:
//   d2: sq=(x2+y2)+z2 seq; dot=fma(z,z',fma(y,y',x*x')); d2=(sqn+sqm)-(2*dot)
//   selection: ascending-j scan, admission `d2 < ld[15]` (strict, d2-only),
//   16-deep displaced-carry insert chain comparing d2 ONLY (the equal-d2
//   scramble is part of the oracle — stable top-16 provably fails, r19).
//
// r21 REPLAY THEOREM (parallelization without changing dynamics):
//   Let T = 16th smallest d2 (multiset property — any correct selection).
//   Candidates with d2 > T never rotate/evict the boundary tie group and
//   admission of d2<=T candidates is gated only by count(<=T so far)<16.
//   Hence running the VERBATIM r17 chain over the ascending-j subsequence
//   {j : d2(j) <= T} yields a bit-identical final list.
//   Phase 1: 8 partitions/query, exact lexicographic (d2,j) top-20 lists.
//   Phase 2: merge 16 pops -> T; collect all <=T (<=19 by tie census,
//   CAP=24 margin); sort by j; replay r17 chain.
// ---------------------------------------------------------------------------

__global__ __launch_bounds__(256) void proj3_kernel(
    const float* __restrict__ x, const float* __restrict__ Wq,
    const float* __restrict__ Wk, const float* __restrict__ Wv,
    float* __restrict__ qf, float* __restrict__ kf, float* __restrict__ vf) {
  int g = blockIdx.x * 256 + threadIdx.x;
  int r = g >> 6, c = g & 63;
  float sq = 0.f, sk = 0.f, sv = 0.f;
  for (int i = 0; i < 64; ++i) {
    float xv = x[r*64 + i];
    sq += xv * Wq[i*64 + c];
    sk += xv * Wk[i*64 + c];
    sv += xv * Wv[i*64 + c];
  }
  qf[g] = sq; kf[g] = sk; vf[g] = sv;
}

// ---------------------------------------------------------------------------
__global__ __launch_bounds__(256) void knn_replay_kernel(
    const float* __restrict__ pos, int* __restrict__ idx_out) {
  __shared__ __align__(16) char smem[65536];
  float4* s_p = (float4*)smem;                 // (x,y,z,sq), 64 KB, phase 1
  int tid = threadIdx.x, b = blockIdx.y;
  const float* pb = pos + b*NPTS*3;
  for (int j = tid; j < NPTS; j += 256) {
    float px = pb[j*3+0], py = pb[j*3+1], pz = pb[j*3+2];
    float sq = __fadd_rn(__fadd_rn(__fmul_rn(px,px), __fmul_rn(py,py)),
                         __fmul_rn(pz,pz));
    s_p[j] = make_float4(px, py, pz, sq);
  }
  __syncthreads();
  int q = tid >> 3, t = tid & 7;
  int n = blockIdx.x * 32 + q;
  float4 qp = s_p[n];
  float qx = qp.x, qy = qp.y, qz = qp.z, sqn = qp.w;

  // Phase 1: exact lexicographic (d2, j) top-DEPTH of partition t
  float ld[DEPTH]; int lj[DEPTH];
#pragma unroll
  for (int u = 0; u < DEPTH; ++u) { ld[u] = INFINITY; lj[u] = 0x7fffffff; }
  for (int s = 0; s < NPTS/8; ++s) {
    int j = (s << 3) | t;
    float4 p = s_p[j];
    // V1 arithmetic, verbatim
    float acc = __fmul_rn(qx, p.x);
    acc = __fmaf_rn(qy, p.y, acc);
    acc = __fmaf_rn(qz, p.z, acc);
    float d2 = __fsub_rn(__fadd_rn(sqn, p.w), __fmul_rn(2.0f, acc));
    if (d2 < ld[DEPTH-1] || (d2 == ld[DEPTH-1] && j < lj[DEPTH-1])) {
      float dd = d2; int jj = j;
#pragma unroll
      for (int u = 0; u < DEPTH; ++u) {
        bool sw = (dd < ld[u]) || (dd == ld[u] && jj < lj[u]);
        float nd = sw ? dd : ld[u]; float td = sw ? ld[u] : dd;
        int   nj = sw ? jj : lj[u]; int   tj = sw ? lj[u] : jj;
        ld[u] = nd; lj[u] = nj; dd = td; jj = tj;
      }
    }
  }
  __syncthreads();
  // overlay partition lists on smem (s_p dead): 20 KB + 20 KB
  float* s_ld = (float*)smem;
  int*   s_lj = (int*)(smem + 256*DEPTH*4);
#pragma unroll
  for (int u = 0; u < DEPTH; ++u) {
    s_ld[tid*DEPTH+u] = ld[u]; s_lj[tid*DEPTH+u] = lj[u];
  }
  __syncthreads();

  if (t == 0) {
    int base = tid;   // == q*8
    // (a) T = 16th smallest (lexicographic 8-way merge, 16 pops)
    int cur[8];
#pragma unroll
    for (int p = 0; p < 8; ++p) cur[p] = 0;
    float T = INFINITY;
    for (int k = 0; k < 16; ++k) {
      float bd = INFINITY; int bj = 0x7fffffff; int bp = 0;
#pragma unroll
      for (int p = 0; p < 8; ++p) {
        int o = (base + p)*DEPTH + cur[p];
        float d = s_ld[o]; int j = s_lj[o];
        bool better = (d < bd) || (d == bd && j < bj);
        if (better) { bd = d; bj = j; bp = p; }
      }
      T = bd; cur[bp]++;
    }
    // (b) collect ALL entries with d2 <= T (lists sorted => early break)
    float cd[CAP]; int cj[CAP]; int cnt = 0;
    for (int p = 0; p < 8; ++p) {
      for (int u = 0; u < DEPTH; ++u) {
        int o = (base + p)*DEPTH + u;
        float d = s_ld[o];
        if (d <= T) {
          if (cnt < CAP) { cd[cnt] = d; cj[cnt] = s_lj[o]; ++cnt; }
        } else break;
      }
    }
    // (c) sort collected by j ascending (insertion sort, cnt <= ~19)
    for (int a = 1; a < cnt; ++a) {
      float d = cd[a]; int j = cj[a]; int v = a - 1;
      while (v >= 0 && cj[v] > j) { cd[v+1] = cd[v]; cj[v+1] = cj[v]; --v; }
      cd[v+1] = d; cj[v+1] = j;
    }
    // (d) replay the VERBATIM r17 chain over the filtered subsequence
    float rd[16]; int rj[16];
#pragma unroll
    for (int u = 0; u < 16; ++u) { rd[u] = INFINITY; rj[u] = 0x7fffffff; }
    for (int a = 0; a < cnt; ++a) {
      float d2 = cd[a];
      if (d2 < rd[15]) {                 // r17 admission: strict, d2-only
        float dd = d2; int jj = cj[a];
#pragma unroll
        for (int v = 0; v < 16; ++v) {   // r17 chain: d2-only compare
          bool sw = dd < rd[v];
          float nd = sw ? dd : rd[v]; float td = sw ? rd[v] : dd;
          int   nj = sw ? jj : rj[v]; int   tj = sw ? rj[v] : jj;
          rd[v] = nd; rj[v] = nj; dd = td; jj = tj;
        }
      }
    }
    int* outp = idx_out + (b*NPTS + n)*KNN;
#pragma unroll
    for (int u = 0; u < 16; ++u) outp[u] = b*NPTS + rj[u];  // GLOBAL row idx
  }
}

// ---------------------------------------------------------------------------
// Fused layer: r20 version (known-good), LDS-staged weights.
// ---------------------------------------------------------------------------
__global__ __launch_bounds__(256) void fuse_kernel(
    const float* __restrict__ pos, const int* __restrict__ idx,
    const float* __restrict__ qf, const float* __restrict__ kf,
    const float* __restrict__ vf,
    const float* __restrict__ p_w1, const float* __restrict__ p_b1,
    const float* __restrict__ p_g, const float* __restrict__ p_be,
    const float* __restrict__ p_w2, const float* __restrict__ p_b2,
    const float* __restrict__ a_w1, const float* __restrict__ a_b1,
    const float* __restrict__ a_g, const float* __restrict__ a_be,
    const float* __restrict__ a_w2, const float* __restrict__ a_b2,
    float* __restrict__ out) {
  __shared__ int   s_j[16];
  __shared__ float s_h[16][12];
  __shared__ float s_win[16][64];     // reused as t2 after step 3
  __shared__ float s_ve[16][64];
  __shared__ float s_ai[16][64];
  __shared__ float s_act[16][64];
  __shared__ float s_m[16], s_rs[16];
  __shared__ float s_w1[4096];
  __shared__ float s_w2[4096];
  __shared__ float s_pw2[768];

  int tid = threadIdx.x;
  int p = blockIdx.x;

  for (int e = tid; e < 4096; e += 256) { s_w1[e] = a_w1[e]; s_w2[e] = a_w2[e]; }
  for (int e = tid; e < 768; e += 256) s_pw2[e] = p_w2[e];

  if (tid < 16) {
    int j = idx[p*KNN + tid];
    s_j[tid] = j;
    float rx = pos[p*3+0] - pos[j*3+0];
    float ry = pos[p*3+1] - pos[j*3+1];
    float rz = pos[p*3+2] - pos[j*3+2];
    float hv[12];
    float mean = 0.f;
#pragma unroll
    for (int h = 0; h < 12; ++h) {
      float v = rx*p_w1[h] + ry*p_w1[12+h] + rz*p_w1[24+h] + p_b1[h];
      hv[h] = v; mean += v;
    }
    mean *= (1.0f/12.0f);
    float var = 0.f;
#pragma unroll
    for (int h = 0; h < 12; ++h) { float d = hv[h] - mean; var += d*d; }
    var *= (1.0f/12.0f);
    float rs = rsqrtf(var + LN_EPS);
#pragma unroll
    for (int h = 0; h < 12; ++h) {
      float a = (hv[h] - mean)*rs*p_g[h] + p_be[h];
      s_h[tid][h] = fmaxf(a, 0.f);
    }
  }
  __syncthreads();

  int c = tid & 63, kq = tid >> 6;

  {
    float qv = qf[p*64 + c];
#pragma unroll
    for (int it = 0; it < 4; ++it) {
      int k = it*4 + kq;
      int j = s_j[k];
      float pe = p_b2[c];
#pragma unroll
      for (int h = 0; h < 12; ++h) pe += s_h[k][h] * s_pw2[h*64 + c];
      s_win[k][c] = qv - kf[j*64 + c] + pe;
      s_ve[k][c]  = vf[j*64 + c] + pe;
    }
  }
  __syncthreads();

#pragma unroll
  for (int it = 0; it < 4; ++it) {
    int k = it*4 + kq;
    float s = a_b1[c];
    for (int i = 0; i < 64; ++i) s += s_win[k][i] * s_w1[i*64 + c];
    s_ai[k][c] = s;
  }
  __syncthreads();

  if (tid < 16) {
    float m = 0.f;
    for (int c2 = 0; c2 < 64; ++c2) m += s_ai[tid][c2];
    m *= (1.0f/64.0f);
    float v = 0.f;
    for (int c2 = 0; c2 < 64; ++c2) { float d = s_ai[tid][c2] - m; v += d*d; }
    v *= (1.0f/64.0f);
    s_m[tid] = m; s_rs[tid] = rsqrtf(v + LN_EPS);
  }
  __syncthreads();
#pragma unroll
  for (int it = 0; it < 4; ++it) {
    int k = it*4 + kq;
    s_act[k][c] = fmaxf((s_ai[k][c] - s_m[k])*s_rs[k]*a_g[c] + a_be[c], 0.f);
  }
  __syncthreads();

#pragma unroll
  for (int it = 0; it < 4; ++it) {
    int k = it*4 + kq;
    float s = a_b2[c];
    for (int i = 0; i < 64; ++i) s += s_act[k][i] * s_w2[i*64 + c];
    s_win[k][c] = s;
  }
  __syncthreads();

  if (tid < 64) {
    float mx = -INFINITY;
    for (int k = 0; k < 16; ++k) mx = fmaxf(mx, s_win[k][tid]);
    float se = 0.f, po = 0.f;
    for (int k = 0; k < 16; ++k) {
      float e = expf(s_win[k][tid] - mx);
      se += e; po += e * s_ve[k][tid];
    }
    out[p*64 + tid] = po / se;
  }
}

// ---------------------------------------------------------------------------
extern "C" void kernel_launch(void* const* d_in, const int* in_sizes, int n_in,
                              void* d_out, int out_size, void* d_ws, size_t ws_size,
                              hipStream_t stream) {
  const float* x    = (const float*)d_in[0];
  const float* pos  = (const float*)d_in[1];
  const float* Wq   = (const float*)d_in[2];
  const float* Wk   = (const float*)d_in[3];
  const float* Wv   = (const float*)d_in[4];
  const float* p_w1 = (const float*)d_in[5];
  const float* p_b1 = (const float*)d_in[6];
  const float* p_g  = (const float*)d_in[7];
  const float* p_be = (const float*)d_in[8];
  const float* p_w2 = (const float*)d_in[9];
  const float* p_b2 = (const float*)d_in[10];
  const float* a_w1 = (const float*)d_in[11];
  const float* a_b1 = (const float*)d_in[12];
  const float* a_g  = (const float*)d_in[13];
  const float* a_be = (const float*)d_in[14];
  const float* a_w2 = (const float*)d_in[15];
  const float* a_b2 = (const float*)d_in[16];

  float* ws   = (float*)d_ws;
  float* qf   = ws;                    // 1048576 floats
  float* kf   = qf + 1048576;          // 1048576
  float* vf   = kf + 1048576;          // 1048576
  int*   idx  = (int*)(vf + 1048576);  // 262144 ints
  float* outp = (float*)d_out;

  hipLaunchKernelGGL(proj3_kernel, dim3(4096), dim3(256), 0, stream,
                     x, Wq, Wk, Wv, qf, kf, vf);
  hipLaunchKernelGGL(knn_replay_kernel, dim3(128, 4), dim3(256), 0, stream,
                     pos, idx);
  hipLaunchKernelGGL(fuse_kernel, dim3(16384), dim3(256), 0, stream,
                     pos, idx, qf, kf, vf,
                     p_w1, p_b1, p_g, p_be, p_w2, p_b2,
                     a_w1, a_b1, a_g, a_be, a_w2, a_b2, outp);
}